// Round 3
// baseline (731.076 us; speedup 1.0000x reference)
//
#include <hip/hip_runtime.h>
#include <hip/hip_bf16.h>
#include <stdint.h>

// ---------------- types / helpers ----------------
typedef __bf16 b16x8 __attribute__((ext_vector_type(8)));
typedef float  f32x4 __attribute__((ext_vector_type(4)));

__device__ __forceinline__ unsigned short f2bf(float f) {
    uint32_t u = __float_as_uint(f);
    u += 0x7fffu + ((u >> 16) & 1u);   // RNE
    return (unsigned short)(u >> 16);
}
__device__ __forceinline__ float bf2f(unsigned short s) {
    return __uint_as_float(((uint32_t)s) << 16);
}

// ---------------- input dtype detection ----------------
// Interpret first n raw u16 of `q` as bf16. If the buffer is really f32, the
// LOW u16 of each float has a random exponent byte -> max abs is astronomical.
// True bf16 N(0,1) data maxes out near 4.5. flag[0]=1 => inputs are f32.
__global__ void k_detect(const unsigned short* __restrict__ q, int n, int* __restrict__ flag) {
    float m = 0.f;
    for (int i = threadIdx.x; i < n; i += 256) {
        float f = fabsf(bf2f(q[i]));
        if (!(f < 1e30f)) f = 1e30f;   // NaN/Inf -> huge
        m = fmaxf(m, f);
    }
#pragma unroll
    for (int o = 32; o > 0; o >>= 1) m = fmaxf(m, __shfl_xor(m, o));
    __shared__ float red[4];
    if ((threadIdx.x & 63) == 0) red[threadIdx.x >> 6] = m;
    __syncthreads();
    if (threadIdx.x == 0) {
        m = fmaxf(fmaxf(red[0], red[1]), fmaxf(red[2], red[3]));
        flag[0] = (m > 1e6f) ? 1 : 0;
    }
}

// Load 8 elements at elem_off (elements of the source dtype) as 8 packed bf16.
// f32src: runtime-uniform flag (1 = f32 source, convert; 0 = bf16, copy).
__device__ __forceinline__ uint4 load8in(const void* base, long elem_off, int f32src) {
    if (f32src) {
        const float4* p = (const float4*)((const float*)base + elem_off);
        float4 a = p[0], b = p[1];
        uint4 o;
        o.x = f2bf(a.x) | ((uint32_t)f2bf(a.y) << 16);
        o.y = f2bf(a.z) | ((uint32_t)f2bf(a.w) << 16);
        o.z = f2bf(b.x) | ((uint32_t)f2bf(b.y) << 16);
        o.w = f2bf(b.z) | ((uint32_t)f2bf(b.w) << 16);
        return o;
    }
    return *(const uint4*)((const unsigned short*)base + elem_off);
}

// ---------------- GEMM: C[m,n] = scale * sum_k A[m,k]*B[n,k] (+ bias[n]) ----
// 128x128 tile, BK=32, 256 threads = 4 waves (2x2 of 64x64 each).
// Reg-staged LDS, bf16 MFMA 16x16x32.
// AIN/BIN: 1 = harness input (dtype per flag), 0 = bf16 intermediate.
// MODE 0: bf16 C[m*N+n] (intermediate). MODE 1: bf16 C[n*M+m] (transposed).
// MODE 2: f32 C[m*N+n] (scores). MODE 3: final output, dtype per flag.
template <int MODE, int AIN, int BIN>
__global__ __launch_bounds__(256) void k_gemm(
    const void* __restrict__ A, const void* __restrict__ B,
    const void* __restrict__ bias, void* __restrict__ Cv,
    int M, int N, int K, int ldA, int ldB,
    long sAb, long sBb, long sCb, float scale,
    const int* __restrict__ flagp)
{
    __shared__ unsigned short As[128 * 32];
    __shared__ unsigned short Bs[128 * 32];
    const int fl   = flagp ? flagp[0] : 0;   // uniform
    const int tid  = threadIdx.x;
    const int lane = tid & 63;
    const int wave = tid >> 6;
    const int bm = blockIdx.y * 128;
    const int bn = blockIdx.x * 128;
    const long aoff = (long)blockIdx.z * sAb;
    const long boff = (long)blockIdx.z * sBb;
    const long zC   = (long)blockIdx.z * sCb;
    const int wm = (wave >> 1) * 64;
    const int wn = (wave & 1) * 64;

    f32x4 acc[4][4];
    const f32x4 zero = {0.f, 0.f, 0.f, 0.f};
#pragma unroll
    for (int i = 0; i < 4; ++i)
#pragma unroll
        for (int j = 0; j < 4; ++j) acc[i][j] = zero;

    // chunk c in [0,512): row = c>>2, k-sub = (c&3)*8. Thread handles c=tid, c=256+tid.
    const int r0 = tid >> 2,         kc0 = tid & 3;
    const int r1 = (256 + tid) >> 2, kc1 = (256 + tid) & 3;

    for (int k0 = 0; k0 < K; k0 += 32) {
        uint4 va0 = load8in(A, aoff + (long)(bm + r0) * ldA + k0 + kc0 * 8, AIN ? fl : 0);
        uint4 vb0 = load8in(B, boff + (long)(bn + r0) * ldB + k0 + kc0 * 8, BIN ? fl : 0);
        uint4 va1 = load8in(A, aoff + (long)(bm + r1) * ldA + k0 + kc1 * 8, AIN ? fl : 0);
        uint4 vb1 = load8in(B, boff + (long)(bn + r1) * ldB + k0 + kc1 * 8, BIN ? fl : 0);
        __syncthreads();   // previous iteration's LDS readers done
        *(uint4*)(As + (size_t)tid * 8)         = va0;
        *(uint4*)(Bs + (size_t)tid * 8)         = vb0;
        *(uint4*)(As + (size_t)(256 + tid) * 8) = va1;
        *(uint4*)(Bs + (size_t)(256 + tid) * 8) = vb1;
        __syncthreads();   // LDS tile visible

        b16x8 af[4], bf[4];
#pragma unroll
        for (int i = 0; i < 4; ++i)
            af[i] = *(const b16x8*)(As + (size_t)(wm + i * 16 + (lane & 15)) * 32 + (lane >> 4) * 8);
#pragma unroll
        for (int i = 0; i < 4; ++i)
            bf[i] = *(const b16x8*)(Bs + (size_t)(wn + i * 16 + (lane & 15)) * 32 + (lane >> 4) * 8);

#pragma unroll
        for (int i = 0; i < 4; ++i)
#pragma unroll
            for (int j = 0; j < 4; ++j)
                acc[i][j] = __builtin_amdgcn_mfma_f32_16x16x32_bf16(af[i], bf[j], acc[i][j], 0, 0, 0);
    }

    // epilogue: C/D fragment layout col = lane&15, row = (lane>>4)*4 + r  [m89/m91]
#pragma unroll
    for (int i = 0; i < 4; ++i) {
#pragma unroll
        for (int j = 0; j < 4; ++j) {
            const int m0 = bm + wm + i * 16 + (lane >> 4) * 4;
            const int n  = bn + wn + j * 16 + (lane & 15);
            float bv = 0.f;
            if (MODE != 2 && bias != nullptr)
                bv = fl ? ((const float*)bias)[n] : bf2f(((const unsigned short*)bias)[n]);
            if (MODE == 0) {
                unsigned short* C = (unsigned short*)Cv;
#pragma unroll
                for (int r = 0; r < 4; ++r)
                    C[zC + (long)(m0 + r) * N + n] = f2bf(acc[i][j][r] * scale + bv);
            } else if (MODE == 1) {
                unsigned short* C = (unsigned short*)Cv;
                uint32_t p0 = f2bf(acc[i][j][0] * scale + bv) |
                              ((uint32_t)f2bf(acc[i][j][1] * scale + bv) << 16);
                uint32_t p1 = f2bf(acc[i][j][2] * scale + bv) |
                              ((uint32_t)f2bf(acc[i][j][3] * scale + bv) << 16);
                uint2 val; val.x = p0; val.y = p1;
                *(uint2*)(C + zC + (long)n * M + m0) = val;
            } else if (MODE == 2) {
                float* C = (float*)Cv;
#pragma unroll
                for (int r = 0; r < 4; ++r)
                    C[zC + (long)(m0 + r) * N + n] = acc[i][j][r] * scale;
            } else {   // MODE 3: final output, dtype per flag
                if (fl) {
                    float* C = (float*)Cv;
#pragma unroll
                    for (int r = 0; r < 4; ++r)
                        C[zC + (long)(m0 + r) * N + n] = acc[i][j][r] * scale + bv;
                } else {
                    unsigned short* C = (unsigned short*)Cv;
#pragma unroll
                    for (int r = 0; r < 4; ++r)
                        C[zC + (long)(m0 + r) * N + n] = f2bf(acc[i][j][r] * scale + bv);
                }
            }
        }
    }
}

// ---------------- row softmax over 1024 cols, IN-PLACE ----------------
// Reads f32 row at S + row*1024, writes bf16 probs over the same bytes
// (row becomes 1024 bf16 in the first 2048 bytes; stride stays 2048 shorts).
__global__ __launch_bounds__(256) void k_softmax(float* __restrict__ S) {
    const long row = blockIdx.x;
    float* s = S + row * 1024;
    unsigned short* p = (unsigned short*)s;
    const int tid = threadIdx.x;
    float4 v = ((const float4*)s)[tid];
    float m = fmaxf(fmaxf(v.x, v.y), fmaxf(v.z, v.w));
#pragma unroll
    for (int o = 32; o > 0; o >>= 1) m = fmaxf(m, __shfl_xor(m, o));
    __shared__ float sm[4], ss[4];
    if ((tid & 63) == 0) sm[tid >> 6] = m;
    __syncthreads();
    m = fmaxf(fmaxf(sm[0], sm[1]), fmaxf(sm[2], sm[3]));
    float e0 = __expf(v.x - m), e1 = __expf(v.y - m);
    float e2 = __expf(v.z - m), e3 = __expf(v.w - m);
    float sum = e0 + e1 + e2 + e3;
#pragma unroll
    for (int o = 32; o > 0; o >>= 1) sum += __shfl_xor(sum, o);
    if ((tid & 63) == 0) ss[tid >> 6] = sum;
    __syncthreads();
    float inv = 1.f / (ss[0] + ss[1] + ss[2] + ss[3]);
    uint32_t w0 = f2bf(e0 * inv) | ((uint32_t)f2bf(e1 * inv) << 16);
    uint32_t w1 = f2bf(e2 * inv) | ((uint32_t)f2bf(e3 * inv) << 16);
    uint2 val; val.x = w0; val.y = w1;
    *(uint2*)(p + tid * 4) = val;
}

// ---------------- host ----------------
extern "C" void kernel_launch(void* const* d_in, const int* in_sizes, int n_in,
                              void* d_out, int out_size, void* d_ws, size_t ws_size,
                              hipStream_t stream) {
    (void)in_sizes; (void)n_in; (void)out_size; (void)ws_size;
    const void* q_in = d_in[0];   // [8,2048,512]
    const void* k_in = d_in[1];   // [8,2048,1024]
    const void* v_in = d_in[2];   // [8,2048,1024]
    const void* Wq   = d_in[3];   // [1024,512]
    const void* bq   = d_in[4];
    const void* Wk   = d_in[5];   // [1024,1024]
    const void* bk   = d_in[6];
    const void* Wv   = d_in[7];   // [1024,1024]
    const void* bv   = d_in[8];
    const void* Wo   = d_in[9];   // [1024,1024]
    const void* bo   = d_in[10];

    // workspace: flag(1MB pad) + Qt(32MB) + Kt(32MB) + scores(32MB) = 97MB
    char* ws = (char*)d_ws;
    int*            flag   = (int*)ws;
    unsigned short* Qt     = (unsigned short*)(ws + (1L  << 20));   // [8,1024,2048] bf16
    unsigned short* Kt     = (unsigned short*)(ws + (33L << 20));   // [8,1024,2048] bf16
    float*          scores = (float*)         (ws + (65L << 20));   // [8,1024,1024] f32
    unsigned short* P      = (unsigned short*)scores;               // row i at i*2048 shorts
    unsigned short* attn   = Kt;                                    // alias (Kt dead after scores)
    unsigned short* Vp     = (unsigned short*)d_out;                // [8,2048,1024] bf16 scratch

    dim3 blk(256);
    k_detect<<<1, blk, 0, stream>>>((const unsigned short*)q_in, 4096, flag);

    // Vp[b,s,j] = value@Wv^T + bv       (M=16384 folded, N=1024, K=1024) -> bf16 scratch in d_out
    k_gemm<0, 1, 1><<<dim3(8, 128, 1), blk, 0, stream>>>(
        v_in, Wv, bv, Vp, 16384, 1024, 1024, 1024, 1024, 0, 0, 0, 1.f, flag);
    // Qt[b,i,s] = (query@Wq^T + bq)^T   (z=8, M=2048 (s), N=1024 (i), K=512)
    k_gemm<1, 1, 1><<<dim3(8, 16, 8), blk, 0, stream>>>(
        q_in, Wq, bq, Qt, 2048, 1024, 512, 512, 512,
        2048L * 512, 0, 1024L * 2048, 1.f, flag);
    // Kt[b,j,s] = (key@Wk^T + bk)^T     (z=8, M=2048 (s), N=1024 (j), K=1024)
    k_gemm<1, 1, 1><<<dim3(8, 16, 8), blk, 0, stream>>>(
        k_in, Wk, bk, Kt, 2048, 1024, 1024, 1024, 1024,
        2048L * 1024, 0, 1024L * 2048, 1.f, flag);
    // scores[b,i,j] = (1/8) sum_s Qt[b,i,s]*Kt[b,j,s]  (z=8, M=N=1024, K=2048) -> f32
    k_gemm<2, 0, 0><<<dim3(8, 8, 8), blk, 0, stream>>>(
        Qt, Kt, nullptr, scores, 1024, 1024, 2048, 2048, 2048,
        1024L * 2048, 1024L * 2048, 1024L * 1024, 0.125f, nullptr);
    // softmax over j, in-place -> P (bf16, row stride 2048 shorts)
    k_softmax<<<dim3(8192), blk, 0, stream>>>(scores);
    // attn[b,s,i] = sum_j Vp[b,s,j]*P[b,i,j]  (z=8, M=2048, N=1024, K=1024)
    k_gemm<0, 0, 0><<<dim3(8, 16, 8), blk, 0, stream>>>(
        Vp, P, nullptr, attn, 2048, 1024, 1024, 1024, 2048,
        2048L * 1024, 1024L * 2048, 2048L * 1024, 1.f, nullptr);
    // out = attn@Wo^T + bo -> d_out (dtype per flag)  (M=16384, N=1024, K=1024)
    k_gemm<3, 0, 1><<<dim3(8, 128, 1), blk, 0, stream>>>(
        attn, Wo, bo, d_out, 16384, 1024, 1024, 1024, 1024, 0, 0, 0, 1.f, flag);
}

// Round 4
// 637.615 us; speedup vs baseline: 1.1466x; 1.1466x over previous
//
#include <hip/hip_runtime.h>
#include <hip/hip_bf16.h>
#include <stdint.h>

// ---------------- types / helpers ----------------
typedef __bf16 b16x8 __attribute__((ext_vector_type(8)));
typedef float  f32x4 __attribute__((ext_vector_type(4)));

__device__ __forceinline__ unsigned short f2bf(float f) {
    uint32_t u = __float_as_uint(f);
    u += 0x7fffu + ((u >> 16) & 1u);   // RNE
    return (unsigned short)(u >> 16);
}
__device__ __forceinline__ float bf2f(unsigned short s) {
    return __uint_as_float(((uint32_t)s) << 16);
}

__device__ __forceinline__ void gld16(const unsigned short* g, unsigned short* l) {
    __builtin_amdgcn_global_load_lds(
        (const __attribute__((address_space(1))) void*)g,
        (__attribute__((address_space(3))) void*)l, 16, 0, 0);
}

// ---------------- input dtype detection ----------------
__global__ void k_detect(const unsigned short* __restrict__ q, int n, int* __restrict__ flag) {
    float m = 0.f;
    for (int i = threadIdx.x; i < n; i += 256) {
        float f = fabsf(bf2f(q[i]));
        if (!(f < 1e30f)) f = 1e30f;
        m = fmaxf(m, f);
    }
#pragma unroll
    for (int o = 32; o > 0; o >>= 1) m = fmaxf(m, __shfl_xor(m, o));
    __shared__ float red[4];
    if ((threadIdx.x & 63) == 0) red[threadIdx.x >> 6] = m;
    __syncthreads();
    if (threadIdx.x == 0) {
        m = fmaxf(fmaxf(red[0], red[1]), fmaxf(red[2], red[3]));
        flag[0] = (m > 1e6f) ? 1 : 0;   // 1 => inputs are f32
    }
}

// ---------------- f32/bf16 -> bf16 materialization (8 elems / thread) ------
__global__ __launch_bounds__(256) void k_cvt(const void* __restrict__ src,
                                             unsigned short* __restrict__ dst,
                                             long n8, const int* __restrict__ flag) {
    long i = blockIdx.x * 256L + threadIdx.x;
    long stride = (long)gridDim.x * 256L;
    if (flag[0]) {
        const float4* s = (const float4*)src;
        for (long j = i; j < n8; j += stride) {
            float4 a = s[2 * j], b = s[2 * j + 1];
            uint4 o;
            o.x = f2bf(a.x) | ((uint32_t)f2bf(a.y) << 16);
            o.y = f2bf(a.z) | ((uint32_t)f2bf(a.w) << 16);
            o.z = f2bf(b.x) | ((uint32_t)f2bf(b.y) << 16);
            o.w = f2bf(b.z) | ((uint32_t)f2bf(b.w) << 16);
            ((uint4*)dst)[j] = o;
        }
    } else {
        const uint4* s = (const uint4*)src;
        for (long j = i; j < n8; j += stride) ((uint4*)dst)[j] = s[j];
    }
}

// Load 8 elems at elem_off as packed bf16; f32src runtime-uniform.
__device__ __forceinline__ uint4 load8in(const void* base, long elem_off, int f32src) {
    if (f32src) {
        const float4* p = (const float4*)((const float*)base + elem_off);
        float4 a = p[0], b = p[1];
        uint4 o;
        o.x = f2bf(a.x) | ((uint32_t)f2bf(a.y) << 16);
        o.y = f2bf(a.z) | ((uint32_t)f2bf(a.w) << 16);
        o.z = f2bf(b.x) | ((uint32_t)f2bf(b.y) << 16);
        o.w = f2bf(b.z) | ((uint32_t)f2bf(b.w) << 16);
        return o;
    }
    return *(const uint4*)((const unsigned short*)base + elem_off);
}

// ---------------- GEMM: C[m,n] = scale * sum_k A[m,k]*B[n,k] (+ bias[n]) ----
// 128x128 tile, BK=32, 256 threads = 4 waves (2x2 of 64x64).
// A: bf16, staged via global_load_lds width-16 (async, no VGPR round-trip).
// B: BGLD=1 -> bf16 via global_load_lds; BGLD=0 -> reg-staged, dtype per flag.
// MODE 0: bf16 C[m*N+n]. MODE 1: bf16 C[n*M+m] (transposed). MODE 2: f32 C.
// MODE 3: final output, dtype per flag (f32 when flag=1).
template <int MODE, int BGLD>
__global__ __launch_bounds__(256) void k_gemm(
    const unsigned short* __restrict__ A, const void* __restrict__ B,
    const void* __restrict__ bias, void* __restrict__ Cv,
    int M, int N, int K, int ldA, int ldB,
    long sAb, long sBb, long sCb, float scale,
    const int* __restrict__ flagp)
{
    __shared__ unsigned short As[128 * 32];
    __shared__ unsigned short Bs[128 * 32];
    const int fl   = flagp ? flagp[0] : 0;
    const int tid  = threadIdx.x;
    const int lane = tid & 63;
    const int wave = tid >> 6;
    const int bm = blockIdx.y * 128;
    const int bn = blockIdx.x * 128;
    const unsigned short* Ab = A + (long)blockIdx.z * sAb;
    const long boff = (long)blockIdx.z * sBb;
    const unsigned short* Bb = (const unsigned short*)B + boff;
    const long zC   = (long)blockIdx.z * sCb;
    const int wm = (wave >> 1) * 64;
    const int wn = (wave & 1) * 64;

    f32x4 acc[4][4];
    const f32x4 zero = {0.f, 0.f, 0.f, 0.f};
#pragma unroll
    for (int i = 0; i < 4; ++i)
#pragma unroll
        for (int j = 0; j < 4; ++j) acc[i][j] = zero;

    // chunk c in [0,512): row = c>>2, k-sub = (c&3)*8. Thread handles c=tid, c=256+tid.
    const int r0 = tid >> 2,         kc0 = tid & 3;
    const int r1 = (256 + tid) >> 2, kc1 = (256 + tid) & 3;

    for (int k0 = 0; k0 < K; k0 += 32) {
        uint4 vb0, vb1;
        if (!BGLD) {   // register-stage B (weights), dtype per flag
            vb0 = load8in(B, boff + (long)(bn + r0) * ldB + k0 + kc0 * 8, fl);
            vb1 = load8in(B, boff + (long)(bn + r1) * ldB + k0 + kc1 * 8, fl);
        }
        __syncthreads();   // previous iteration's LDS readers done
        gld16(Ab + (long)(bm + r0) * ldA + k0 + kc0 * 8, As + (size_t)tid * 8);
        gld16(Ab + (long)(bm + r1) * ldA + k0 + kc1 * 8, As + (size_t)(256 + tid) * 8);
        if (BGLD) {
            gld16(Bb + (long)(bn + r0) * ldB + k0 + kc0 * 8, Bs + (size_t)tid * 8);
            gld16(Bb + (long)(bn + r1) * ldB + k0 + kc1 * 8, Bs + (size_t)(256 + tid) * 8);
        } else {
            *(uint4*)(Bs + (size_t)tid * 8)         = vb0;
            *(uint4*)(Bs + (size_t)(256 + tid) * 8) = vb1;
        }
        __syncthreads();   // drains vmcnt+lgkm -> tiles ready

        b16x8 af[4], bf[4];
#pragma unroll
        for (int i = 0; i < 4; ++i)
            af[i] = *(const b16x8*)(As + (size_t)(wm + i * 16 + (lane & 15)) * 32 + (lane >> 4) * 8);
#pragma unroll
        for (int i = 0; i < 4; ++i)
            bf[i] = *(const b16x8*)(Bs + (size_t)(wn + i * 16 + (lane & 15)) * 32 + (lane >> 4) * 8);

#pragma unroll
        for (int i = 0; i < 4; ++i)
#pragma unroll
            for (int j = 0; j < 4; ++j)
                acc[i][j] = __builtin_amdgcn_mfma_f32_16x16x32_bf16(af[i], bf[j], acc[i][j], 0, 0, 0);
    }

    // epilogue: C/D fragment layout col = lane&15, row = (lane>>4)*4 + r  [m89/m91]
#pragma unroll
    for (int i = 0; i < 4; ++i) {
#pragma unroll
        for (int j = 0; j < 4; ++j) {
            const int m0 = bm + wm + i * 16 + (lane >> 4) * 4;
            const int n  = bn + wn + j * 16 + (lane & 15);
            float bv = 0.f;
            if (MODE != 2 && bias != nullptr)
                bv = fl ? ((const float*)bias)[n] : bf2f(((const unsigned short*)bias)[n]);
            if (MODE == 0) {
                unsigned short* C = (unsigned short*)Cv;
#pragma unroll
                for (int r = 0; r < 4; ++r)
                    C[zC + (long)(m0 + r) * N + n] = f2bf(acc[i][j][r] * scale + bv);
            } else if (MODE == 1) {
                unsigned short* C = (unsigned short*)Cv;
                uint32_t p0 = f2bf(acc[i][j][0] * scale + bv) |
                              ((uint32_t)f2bf(acc[i][j][1] * scale + bv) << 16);
                uint32_t p1 = f2bf(acc[i][j][2] * scale + bv) |
                              ((uint32_t)f2bf(acc[i][j][3] * scale + bv) << 16);
                uint2 val; val.x = p0; val.y = p1;
                *(uint2*)(C + zC + (long)n * M + m0) = val;
            } else if (MODE == 2) {
                float* C = (float*)Cv;
#pragma unroll
                for (int r = 0; r < 4; ++r)
                    C[zC + (long)(m0 + r) * N + n] = acc[i][j][r] * scale;
            } else {
                if (fl) {
                    float* C = (float*)Cv;
#pragma unroll
                    for (int r = 0; r < 4; ++r)
                        C[zC + (long)(m0 + r) * N + n] = acc[i][j][r] * scale + bv;
                } else {
                    unsigned short* C = (unsigned short*)Cv;
#pragma unroll
                    for (int r = 0; r < 4; ++r)
                        C[zC + (long)(m0 + r) * N + n] = f2bf(acc[i][j][r] * scale + bv);
                }
            }
        }
    }
}

// ---------------- row softmax over 1024 cols, IN-PLACE ----------------
__global__ __launch_bounds__(256) void k_softmax(float* __restrict__ S) {
    const long row = blockIdx.x;
    float* s = S + row * 1024;
    unsigned short* p = (unsigned short*)s;
    const int tid = threadIdx.x;
    float4 v = ((const float4*)s)[tid];
    float m = fmaxf(fmaxf(v.x, v.y), fmaxf(v.z, v.w));
#pragma unroll
    for (int o = 32; o > 0; o >>= 1) m = fmaxf(m, __shfl_xor(m, o));
    __shared__ float sm[4], ss[4];
    if ((tid & 63) == 0) sm[tid >> 6] = m;
    __syncthreads();
    m = fmaxf(fmaxf(sm[0], sm[1]), fmaxf(sm[2], sm[3]));
    float e0 = __expf(v.x - m), e1 = __expf(v.y - m);
    float e2 = __expf(v.z - m), e3 = __expf(v.w - m);
    float sum = e0 + e1 + e2 + e3;
#pragma unroll
    for (int o = 32; o > 0; o >>= 1) sum += __shfl_xor(sum, o);
    if ((tid & 63) == 0) ss[tid >> 6] = sum;
    __syncthreads();
    float inv = 1.f / (ss[0] + ss[1] + ss[2] + ss[3]);
    uint32_t w0 = f2bf(e0 * inv) | ((uint32_t)f2bf(e1 * inv) << 16);
    uint32_t w1 = f2bf(e2 * inv) | ((uint32_t)f2bf(e3 * inv) << 16);
    uint2 val; val.x = w0; val.y = w1;
    *(uint2*)(p + tid * 4) = val;
}

// ---------------- host ----------------
extern "C" void kernel_launch(void* const* d_in, const int* in_sizes, int n_in,
                              void* d_out, int out_size, void* d_ws, size_t ws_size,
                              hipStream_t stream) {
    (void)in_sizes; (void)n_in; (void)out_size; (void)ws_size;
    const void* q_in = d_in[0];   // [8,2048,512]
    const void* k_in = d_in[1];   // [8,2048,1024]
    const void* v_in = d_in[2];   // [8,2048,1024]
    const void* Wq   = d_in[3];   // [1024,512]
    const void* bq   = d_in[4];
    const void* Wk   = d_in[5];   // [1024,1024]
    const void* bk   = d_in[6];
    const void* Wv   = d_in[7];   // [1024,1024]
    const void* bv   = d_in[8];
    const void* Wo   = d_in[9];   // [1024,1024]
    const void* bo   = d_in[10];

    // workspace (97 MB proven footprint): flag pad 1MB + three 32MB regions.
    // Lifetimes: R1 = kb -> qb -> vb -> scores/P ; R2 = Kt -> attn ; R3 = Qt.
    char* ws = (char*)d_ws;
    const size_t MB = 1u << 20;
    int*            flag = (int*)ws;
    unsigned short* R1   = (unsigned short*)(ws + 1 * MB);
    unsigned short* R2   = (unsigned short*)(ws + 33 * MB);
    unsigned short* R3   = (unsigned short*)(ws + 65 * MB);
    unsigned short* kb = R1, *qb = R1, *vb = R1;
    unsigned short* Kt = R2, *attn = R2;
    unsigned short* Qt = R3;
    float*          scores = (float*)R1;
    unsigned short* P      = R1;                       // row i at i*2048 shorts
    unsigned short* Vp     = (unsigned short*)d_out;   // [8,2048,1024] bf16 (first 32MB of 64MB f32 out)

    dim3 blk(256);
    k_detect<<<1, blk, 0, stream>>>((const unsigned short*)q_in, 4096, flag);

    // --- K path ---
    k_cvt<<<2048, blk, 0, stream>>>(k_in, kb, (8L * 2048 * 1024) / 8, flag);
    k_gemm<1, 0><<<dim3(8, 16, 8), blk, 0, stream>>>(      // Kt[b,j,s]
        kb, Wk, bk, Kt, 2048, 1024, 1024, 1024, 1024,
        2048L * 1024, 0, 1024L * 2048, 1.f, flag);
    // --- Q path ---
    k_cvt<<<2048, blk, 0, stream>>>(q_in, qb, (8L * 2048 * 512) / 8, flag);
    k_gemm<1, 0><<<dim3(8, 16, 8), blk, 0, stream>>>(      // Qt[b,i,s]
        qb, Wq, bq, Qt, 2048, 1024, 512, 512, 512,
        2048L * 512, 0, 1024L * 2048, 1.f, flag);
    // --- V path ---
    k_cvt<<<2048, blk, 0, stream>>>(v_in, vb, (8L * 2048 * 1024) / 8, flag);
    k_gemm<0, 0><<<dim3(8, 128, 1), blk, 0, stream>>>(     // Vp[b,s,j] (M folded)
        vb, Wv, bv, Vp, 16384, 1024, 1024, 1024, 1024, 0, 0, 0, 1.f, flag);
    // --- scores[b,i,j] = (1/8) sum_s Qt[b,i,s]*Kt[b,j,s] -> f32 ---
    k_gemm<2, 1><<<dim3(8, 8, 8), blk, 0, stream>>>(
        Qt, Kt, nullptr, scores, 1024, 1024, 2048, 2048, 2048,
        1024L * 2048, 1024L * 2048, 1024L * 1024, 0.125f, nullptr);
    // --- softmax over j, in-place -> P (bf16, row stride 2048 shorts) ---
    k_softmax<<<dim3(8192), blk, 0, stream>>>(scores);
    // --- attn[b,s,i] = sum_j Vp[b,s,j]*P[b,i,j] ---
    k_gemm<0, 1><<<dim3(8, 16, 8), blk, 0, stream>>>(
        Vp, P, nullptr, attn, 2048, 1024, 1024, 1024, 2048,
        2048L * 1024, 1024L * 2048, 2048L * 1024, 1.f, nullptr);
    // --- out = attn@Wo^T + bo -> d_out (f32 per flag) ---
    k_gemm<3, 0><<<dim3(8, 128, 1), blk, 0, stream>>>(
        attn, Wo, bo, d_out, 16384, 1024, 1024, 1024, 1024, 0, 0, 0, 1.f, flag);
}

// Round 5
// 322.036 us; speedup vs baseline: 2.2702x; 1.9800x over previous
//
#include <hip/hip_runtime.h>
#include <hip/hip_bf16.h>
#include <stdint.h>

// ---------------- types / helpers ----------------
typedef __bf16 b16x8 __attribute__((ext_vector_type(8)));
typedef float  f32x4 __attribute__((ext_vector_type(4)));

__device__ __forceinline__ unsigned short f2bf(float f) {
    uint32_t u = __float_as_uint(f);
    u += 0x7fffu + ((u >> 16) & 1u);   // RNE
    return (unsigned short)(u >> 16);
}
__device__ __forceinline__ float bf2f(unsigned short s) {
    return __uint_as_float(((uint32_t)s) << 16);
}

__device__ __forceinline__ void gld16(const unsigned short* g, unsigned short* l) {
    __builtin_amdgcn_global_load_lds(
        (const __attribute__((address_space(1))) void*)g,
        (__attribute__((address_space(3))) void*)l, 16, 0, 0);
}

// ---------------- input dtype detection ----------------
__global__ void k_detect(const unsigned short* __restrict__ q, int n, int* __restrict__ flag) {
    float m = 0.f;
    for (int i = threadIdx.x; i < n; i += 256) {
        float f = fabsf(bf2f(q[i]));
        if (!(f < 1e30f)) f = 1e30f;
        m = fmaxf(m, f);
    }
#pragma unroll
    for (int o = 32; o > 0; o >>= 1) m = fmaxf(m, __shfl_xor(m, o));
    __shared__ float red[4];
    if ((threadIdx.x & 63) == 0) red[threadIdx.x >> 6] = m;
    __syncthreads();
    if (threadIdx.x == 0) {
        m = fmaxf(fmaxf(red[0], red[1]), fmaxf(red[2], red[3]));
        flag[0] = (m > 1e6f) ? 1 : 0;   // 1 => inputs are f32
    }
}

// ---------------- f32/bf16 -> bf16 materialization (8 elems / thread) ------
__global__ __launch_bounds__(256) void k_cvt(const void* __restrict__ src,
                                             unsigned short* __restrict__ dst,
                                             long n8, const int* __restrict__ flag) {
    long i = blockIdx.x * 256L + threadIdx.x;
    long stride = (long)gridDim.x * 256L;
    if (flag[0]) {
        const float4* s = (const float4*)src;
        for (long j = i; j < n8; j += stride) {
            float4 a = s[2 * j], b = s[2 * j + 1];
            uint4 o;
            o.x = f2bf(a.x) | ((uint32_t)f2bf(a.y) << 16);
            o.y = f2bf(a.z) | ((uint32_t)f2bf(a.w) << 16);
            o.z = f2bf(b.x) | ((uint32_t)f2bf(b.y) << 16);
            o.w = f2bf(b.z) | ((uint32_t)f2bf(b.w) << 16);
            ((uint4*)dst)[j] = o;
        }
    } else {
        const uint4* s = (const uint4*)src;
        for (long j = i; j < n8; j += stride) ((uint4*)dst)[j] = s[j];
    }
}

// biases -> f32 (4 x 1024)
__global__ __launch_bounds__(256) void k_cvt_bias(const void* b0, const void* b1,
                                                  const void* b2, const void* b3,
                                                  float* __restrict__ dst,
                                                  const int* __restrict__ flag) {
    int i = blockIdx.x * 256 + threadIdx.x;   // 4096 threads
    int which = i >> 10, idx = i & 1023;
    const void* src = (which == 0) ? b0 : (which == 1) ? b1 : (which == 2) ? b2 : b3;
    dst[i] = flag[0] ? ((const float*)src)[idx] : bf2f(((const unsigned short*)src)[idx]);
}

// ---------------- GEMM2: C[m,n] = scale*sum_k A[m,k]*B[n,k] (+bias[n]) -----
// 256x256 tile, BK=64, 512 threads = 8 waves (2M x 4N, each 128x64 output).
// Double-buffered LDS (128 KiB dynamic), global_load_lds staging for A and B
// with XOR-permuted per-lane SOURCE addresses so ds_read_b128 is 2-way
// conflict-free (klo' = klo ^ (row&7)); LDS stays lane-linear (m104/m173).
// Per K-tile: issue 8 prefetch loads for t+1, 4 phases x 16 MFMA, ONE barrier.
// Batch z folded into grid.y: batch = bm>>lb, row-in-batch = bm&((1<<lb)-1).
// MODE 0: bf16 C[zC + r*N + n]. MODE 1: bf16 C[zC + n*Mb + r] (transposed).
// MODE 2: f32 C (scale, no bias). MODE 3: output dtype per flag (+bias).
template <int MODE>
__global__ __launch_bounds__(512, 2) void k_gemm2(
    const unsigned short* __restrict__ A, const unsigned short* __restrict__ B,
    const float* __restrict__ bias, void* __restrict__ Cv,
    int N, int K, int ldA, int ldB, int lb,
    long sAb, long sBb, long sCb, float scale,
    const int* __restrict__ flagp)
{
    extern __shared__ unsigned short lds_raw[];   // [buf][op][2048 chunks * 8]
    const int tid  = threadIdx.x;
    const int lane = tid & 63;
    const int wave = tid >> 6;
    const int bn = blockIdx.x * 256;
    const int bm = blockIdx.y * 256;              // virtual row base
    const int batch = bm >> lb;
    const int am0 = bm & ((1 << lb) - 1);
    const int Mb = 1 << lb;
    const unsigned short* Ab = A + (long)batch * sAb;
    const unsigned short* Bb = B + (long)batch * sBb;
    const long zC = (long)batch * sCb;
    const int wm = (wave >> 2) * 128;
    const int wn = (wave & 3) * 64;

    f32x4 acc[8][4];
    const f32x4 zero = {0.f, 0.f, 0.f, 0.f};
#pragma unroll
    for (int i = 0; i < 8; ++i)
#pragma unroll
        for (int j = 0; j < 4; ++j) acc[i][j] = zero;

    // stage K-tile kt (both operands) into buffer cb. 2048 16B-chunks/operand,
    // 4 per thread. LDS dest lane-linear; global source XOR-permuted.
    auto stage = [&](int kt, int cb) {
        unsigned short* LA = lds_raw + (size_t)cb * 32768;
        unsigned short* LB = LA + 16384;
#pragma unroll
        for (int j = 0; j < 4; ++j) {
            const int d = j * 512 + tid;
            const int row = d >> 3;
            const int klo = (d & 7) ^ (row & 7);
            gld16(Ab + (long)(am0 + row) * ldA + kt * 64 + klo * 8, LA + (size_t)d * 8);
            gld16(Bb + (long)(bn + row) * ldB + kt * 64 + klo * 8, LB + (size_t)d * 8);
        }
    };

    // compute one K-tile from buffer cb: 4 phases x (4 ds_read A + 16 MFMA)
    auto ctile = [&](int cb) {
        const unsigned short* LA = lds_raw + (size_t)cb * 32768;
        const unsigned short* LB = LA + 16384;
        b16x8 bfr[4][2];
#pragma unroll
        for (int p = 0; p < 4; ++p) {
            if (p == 0) {
#pragma unroll
                for (int j = 0; j < 4; ++j)
#pragma unroll
                    for (int s = 0; s < 2; ++s) {
                        const int r = wn + j * 16 + (lane & 15);
                        const int kl = s * 4 + (lane >> 4);
                        bfr[j][s] = *(const b16x8*)(LB + ((size_t)r * 8 + (kl ^ (r & 7))) * 8);
                    }
            }
            b16x8 a[2][2];
#pragma unroll
            for (int q = 0; q < 2; ++q)
#pragma unroll
                for (int s = 0; s < 2; ++s) {
                    const int r = wm + (2 * p + q) * 16 + (lane & 15);
                    const int kl = s * 4 + (lane >> 4);
                    a[q][s] = *(const b16x8*)(LA + ((size_t)r * 8 + (kl ^ (r & 7))) * 8);
                }
            __builtin_amdgcn_s_setprio(1);
#pragma unroll
            for (int q = 0; q < 2; ++q)
#pragma unroll
                for (int j = 0; j < 4; ++j)
#pragma unroll
                    for (int s = 0; s < 2; ++s)
                        acc[2 * p + q][j] = __builtin_amdgcn_mfma_f32_16x16x32_bf16(
                            a[q][s], bfr[j][s], acc[2 * p + q][j], 0, 0, 0);
            __builtin_amdgcn_s_setprio(0);
        }
    };

    const int NT = K >> 6;
    stage(0, 0);
    __syncthreads();                 // drain -> tile 0 in LDS
    int cur = 0;
    for (int kt = 0; kt < NT - 1; ++kt) {
        stage(kt + 1, cur ^ 1);      // prefetch next tile (issued before compute)
        ctile(cur);                  // 64 MFMA of cover
        __syncthreads();             // drain vm+lgkm, swap
        cur ^= 1;
    }
    ctile(cur);                      // last tile, no prefetch

    const int fl = flagp ? flagp[0] : 1;
#pragma unroll
    for (int i = 0; i < 8; ++i)
#pragma unroll
        for (int j = 0; j < 4; ++j) {
            const int rloc = am0 + wm + i * 16 + (lane >> 4) * 4;
            const int n    = bn + wn + j * 16 + (lane & 15);
            const float bv = (MODE != 2 && bias != nullptr) ? bias[n] : 0.f;
            if (MODE == 0) {
                unsigned short* C = (unsigned short*)Cv;
#pragma unroll
                for (int r = 0; r < 4; ++r)
                    C[zC + (long)(rloc + r) * N + n] = f2bf(acc[i][j][r] * scale + bv);
            } else if (MODE == 1) {
                unsigned short* C = (unsigned short*)Cv;
                uint32_t p0 = f2bf(acc[i][j][0] * scale + bv) |
                              ((uint32_t)f2bf(acc[i][j][1] * scale + bv) << 16);
                uint32_t p1 = f2bf(acc[i][j][2] * scale + bv) |
                              ((uint32_t)f2bf(acc[i][j][3] * scale + bv) << 16);
                uint2 val; val.x = p0; val.y = p1;
                *(uint2*)(C + zC + (long)n * Mb + rloc) = val;
            } else if (MODE == 2) {
                float* C = (float*)Cv;
#pragma unroll
                for (int r = 0; r < 4; ++r)
                    C[zC + (long)(rloc + r) * N + n] = acc[i][j][r] * scale;
            } else {
                if (fl) {
                    float* C = (float*)Cv;
#pragma unroll
                    for (int r = 0; r < 4; ++r)
                        C[zC + (long)(rloc + r) * N + n] = acc[i][j][r] * scale + bv;
                } else {
                    unsigned short* C = (unsigned short*)Cv;
#pragma unroll
                    for (int r = 0; r < 4; ++r)
                        C[zC + (long)(rloc + r) * N + n] = f2bf(acc[i][j][r] * scale + bv);
                }
            }
        }
}

// ---------------- row softmax over 1024 cols, IN-PLACE ----------------
__global__ __launch_bounds__(256) void k_softmax(float* __restrict__ S) {
    const long row = blockIdx.x;
    float* s = S + row * 1024;
    unsigned short* p = (unsigned short*)s;
    const int tid = threadIdx.x;
    float4 v = ((const float4*)s)[tid];
    float m = fmaxf(fmaxf(v.x, v.y), fmaxf(v.z, v.w));
#pragma unroll
    for (int o = 32; o > 0; o >>= 1) m = fmaxf(m, __shfl_xor(m, o));
    __shared__ float sm[4], ss[4];
    if ((tid & 63) == 0) sm[tid >> 6] = m;
    __syncthreads();
    m = fmaxf(fmaxf(sm[0], sm[1]), fmaxf(sm[2], sm[3]));
    float e0 = __expf(v.x - m), e1 = __expf(v.y - m);
    float e2 = __expf(v.z - m), e3 = __expf(v.w - m);
    float sum = e0 + e1 + e2 + e3;
#pragma unroll
    for (int o = 32; o > 0; o >>= 1) sum += __shfl_xor(sum, o);
    if ((tid & 63) == 0) ss[tid >> 6] = sum;
    __syncthreads();
    float inv = 1.f / (ss[0] + ss[1] + ss[2] + ss[3]);
    uint32_t w0 = f2bf(e0 * inv) | ((uint32_t)f2bf(e1 * inv) << 16);
    uint32_t w1 = f2bf(e2 * inv) | ((uint32_t)f2bf(e3 * inv) << 16);
    uint2 val; val.x = w0; val.y = w1;
    *(uint2*)(p + tid * 4) = val;
}

// ---------------- host ----------------
extern "C" void kernel_launch(void* const* d_in, const int* in_sizes, int n_in,
                              void* d_out, int out_size, void* d_ws, size_t ws_size,
                              hipStream_t stream) {
    (void)in_sizes; (void)n_in; (void)out_size; (void)ws_size;
    const void* q_in = d_in[0];   // [8,2048,512]
    const void* k_in = d_in[1];   // [8,2048,1024]
    const void* v_in = d_in[2];   // [8,2048,1024]
    const void* Wq   = d_in[3];   // [1024,512]
    const void* bq   = d_in[4];
    const void* Wk   = d_in[5];   // [1024,1024]
    const void* bk   = d_in[6];
    const void* Wv   = d_in[7];   // [1024,1024]
    const void* bv   = d_in[8];
    const void* Wo   = d_in[9];   // [1024,1024]
    const void* bo   = d_in[10];

    const size_t MB = 1u << 20;
    const size_t LDSB = 131072;   // 128 KiB dynamic LDS
    hipFuncSetAttribute((const void*)k_gemm2<0>, hipFuncAttributeMaxDynamicSharedMemorySize, (int)LDSB);
    hipFuncSetAttribute((const void*)k_gemm2<1>, hipFuncAttributeMaxDynamicSharedMemorySize, (int)LDSB);
    hipFuncSetAttribute((const void*)k_gemm2<2>, hipFuncAttributeMaxDynamicSharedMemorySize, (int)LDSB);
    hipFuncSetAttribute((const void*)k_gemm2<3>, hipFuncAttributeMaxDynamicSharedMemorySize, (int)LDSB);

    // workspace (97 MB proven): flag pad 1MB + R1(32) + R2(32) + R3(32).
    // R1: kb -> qb -> vb -> scores/P.  R2: Kt -> attn.  R3: weights bf16 + bias f32.
    // d_out: [0,32MB) Vp bf16 scratch; [32,64MB) Qt bf16 scratch; final f32 overwrites all.
    char* ws = (char*)d_ws;
    int*            flag = (int*)ws;
    unsigned short* R1   = (unsigned short*)(ws + 1 * MB);
    unsigned short* R2   = (unsigned short*)(ws + 33 * MB);
    char*           R3   = ws + 65 * MB;
    unsigned short* kb = R1, *qb = R1, *vb = R1;
    unsigned short* Kt = R2, *attn = R2;
    float*          scores = (float*)R1;
    unsigned short* P      = R1;                        // row i at i*2048 shorts
    unsigned short* wqb = (unsigned short*)R3;          // 1MB
    unsigned short* wkb = (unsigned short*)(R3 + 1 * MB);
    unsigned short* wvb = (unsigned short*)(R3 + 3 * MB);
    unsigned short* wob = (unsigned short*)(R3 + 5 * MB);
    float*          bias4 = (float*)(R3 + 7 * MB);      // bq,bk,bv,bo (f32)
    unsigned short* Vp = (unsigned short*)d_out;                     // [8,2048,1024] bf16
    unsigned short* Qt = (unsigned short*)((char*)d_out + 32 * MB);  // [8,1024,2048] bf16

    dim3 blk(256);
    k_detect<<<1, blk, 0, stream>>>((const unsigned short*)q_in, 4096, flag);
    k_cvt_bias<<<16, blk, 0, stream>>>(bq, bk, bv, bo, bias4, flag);
    k_cvt<<<256, blk, 0, stream>>>(Wq, wqb, 1024L * 512 / 8, flag);
    k_cvt<<<512, blk, 0, stream>>>(Wk, wkb, 1024L * 1024 / 8, flag);
    k_cvt<<<512, blk, 0, stream>>>(Wv, wvb, 1024L * 1024 / 8, flag);
    k_cvt<<<512, blk, 0, stream>>>(Wo, wob, 1024L * 1024 / 8, flag);

    dim3 blk5(512);
    // K path: kb -> Kt[b,j,s]
    k_cvt<<<2048, blk, 0, stream>>>(k_in, kb, 8L * 2048 * 1024 / 8, flag);
    k_gemm2<1><<<dim3(4, 64), blk5, LDSB, stream>>>(
        kb, wkb, bias4 + 1024, Kt, 1024, 1024, 1024, 1024, 11,
        2048L * 1024, 0, 1024L * 2048, 1.f, nullptr);
    // Q path: qb -> Qt[b,i,s]
    k_cvt<<<2048, blk, 0, stream>>>(q_in, qb, 8L * 2048 * 512 / 8, flag);
    k_gemm2<1><<<dim3(4, 64), blk5, LDSB, stream>>>(
        qb, wqb, bias4, Qt, 1024, 512, 512, 512, 11,
        2048L * 512, 0, 1024L * 2048, 1.f, nullptr);
    // V path: vb -> Vp[b,s,j] (M folded 16384, single batch)
    k_cvt<<<2048, blk, 0, stream>>>(v_in, vb, 8L * 2048 * 1024 / 8, flag);
    k_gemm2<0><<<dim3(4, 64), blk5, LDSB, stream>>>(
        vb, wvb, bias4 + 2 * 1024, Vp, 1024, 1024, 1024, 1024, 24,
        0, 0, 0, 1.f, nullptr);
    // scores[b,i,j] = (1/8) sum_s Qt[b,i,s]*Kt[b,j,s]  (M=8 x 1024, K=2048) -> f32
    k_gemm2<2><<<dim3(4, 32), blk5, LDSB, stream>>>(
        Qt, Kt, nullptr, scores, 1024, 2048, 2048, 2048, 10,
        1024L * 2048, 1024L * 2048, 1024L * 1024, 0.125f, nullptr);
    // softmax over j, in-place -> P (bf16, row stride 2048 shorts)
    k_softmax<<<dim3(8192), blk, 0, stream>>>(scores);
    // attn[b,s,i] = sum_j Vp[b,s,j]*P[b,i,j]  (M=8 x 2048, K=1024)
    k_gemm2<0><<<dim3(4, 64), blk5, LDSB, stream>>>(
        Vp, P, nullptr, attn, 1024, 1024, 1024, 2048, 11,
        2048L * 1024, 1024L * 2048, 2048L * 1024, 1.f, nullptr);
    // out = attn@Wo^T + bo -> d_out (f32 per flag)  (M=16384 single batch, K=1024)
    k_gemm2<3><<<dim3(4, 64), blk5, LDSB, stream>>>(
        attn, wob, bias4 + 3 * 1024, d_out, 1024, 1024, 1024, 1024, 24,
        0, 0, 0, 1.f, flag);
}

// Round 6
// 319.018 us; speedup vs baseline: 2.2916x; 1.0095x over previous
//
#include <hip/hip_runtime.h>
#include <hip/hip_bf16.h>
#include <stdint.h>

// ---------------- types / helpers ----------------
typedef __bf16 b16x8 __attribute__((ext_vector_type(8)));
typedef float  f32x4 __attribute__((ext_vector_type(4)));

__device__ __forceinline__ unsigned short f2bf(float f) {
    uint32_t u = __float_as_uint(f);
    u += 0x7fffu + ((u >> 16) & 1u);   // RNE
    return (unsigned short)(u >> 16);
}
__device__ __forceinline__ float bf2f(unsigned short s) {
    return __uint_as_float(((uint32_t)s) << 16);
}

__device__ __forceinline__ void gld16(const unsigned short* g, unsigned short* l) {
    __builtin_amdgcn_global_load_lds(
        (const __attribute__((address_space(1))) void*)g,
        (__attribute__((address_space(3))) void*)l, 16, 0, 0);
}

// ---------------- input dtype detection ----------------
__global__ void k_detect(const unsigned short* __restrict__ q, int n, int* __restrict__ flag) {
    float m = 0.f;
    for (int i = threadIdx.x; i < n; i += 256) {
        float f = fabsf(bf2f(q[i]));
        if (!(f < 1e30f)) f = 1e30f;
        m = fmaxf(m, f);
    }
#pragma unroll
    for (int o = 32; o > 0; o >>= 1) m = fmaxf(m, __shfl_xor(m, o));
    __shared__ float red[4];
    if ((threadIdx.x & 63) == 0) red[threadIdx.x >> 6] = m;
    __syncthreads();
    if (threadIdx.x == 0) {
        m = fmaxf(fmaxf(red[0], red[1]), fmaxf(red[2], red[3]));
        flag[0] = (m > 1e6f) ? 1 : 0;   // 1 => inputs are f32
    }
}

// ---------------- f32/bf16 -> bf16 materialization (8 elems / thread) ------
__global__ __launch_bounds__(256) void k_cvt(const void* __restrict__ src,
                                             unsigned short* __restrict__ dst,
                                             long n8, const int* __restrict__ flag) {
    long i = blockIdx.x * 256L + threadIdx.x;
    long stride = (long)gridDim.x * 256L;
    if (flag[0]) {
        const float4* s = (const float4*)src;
        for (long j = i; j < n8; j += stride) {
            float4 a = s[2 * j], b = s[2 * j + 1];
            uint4 o;
            o.x = f2bf(a.x) | ((uint32_t)f2bf(a.y) << 16);
            o.y = f2bf(a.z) | ((uint32_t)f2bf(a.w) << 16);
            o.z = f2bf(b.x) | ((uint32_t)f2bf(b.y) << 16);
            o.w = f2bf(b.z) | ((uint32_t)f2bf(b.w) << 16);
            ((uint4*)dst)[j] = o;
        }
    } else {
        const uint4* s = (const uint4*)src;
        for (long j = i; j < n8; j += stride) ((uint4*)dst)[j] = s[j];
    }
}

// biases -> f32 (4 x 1024)
__global__ __launch_bounds__(256) void k_cvt_bias(const void* b0, const void* b1,
                                                  const void* b2, const void* b3,
                                                  float* __restrict__ dst,
                                                  const int* __restrict__ flag) {
    int i = blockIdx.x * 256 + threadIdx.x;   // 4096 threads
    int which = i >> 10, idx = i & 1023;
    const void* src = (which == 0) ? b0 : (which == 1) ? b1 : (which == 2) ? b2 : b3;
    dst[i] = flag[0] ? ((const float*)src)[idx] : bf2f(((const unsigned short*)src)[idx]);
}

// ---------------- GEMM3: C[m,n] = scale*sum_k A[m,k]*B[n,k] (+bias[n]) -----
// 256x256 tile, BK=64, 512 threads = 8 waves (2 M-groups x 4 N-groups).
// Double-buffered LDS (128 KiB), global_load_lds with XOR-permuted SOURCE
// (klo' = klo ^ (row&7)) so ds_read_b128 is conflict-free; LDS lane-linear.
// Counted-vmcnt 4-phase schedule per K-tile (T3+T4), raw s_barrier, setprio.
//  staging quarters (FIFO): Q0=B rows 0-127, Q1=B 128-255, Q2=A 0-127, Q3=A 128-255
//  phase p computes A rows (p>>1)*128 + (p&1)*64 + g*32 + r*16  (g=wave>>2, r=0,1)
//  gates: vmcnt(2) @p0 (allows Q3 in flight), vmcnt(4|0) @p2 (allows next B0,B1).
// XCD-bijective block swizzle (nwg%8==0).
// MODE 0: bf16 C[zC+r*N+n]. MODE 1: bf16 C[zC+n*Mb+r]. MODE 2: f32 C.
// MODE 3: output dtype per flag (+bias).
template <int MODE>
__global__ __launch_bounds__(512, 2) void k_gemm3(
    const unsigned short* __restrict__ A, const unsigned short* __restrict__ B,
    const float* __restrict__ bias, void* __restrict__ Cv,
    int N, int K, int ldA, int ldB, int lb,
    long sAb, long sBb, long sCb, float scale,
    const int* __restrict__ flagp)
{
    extern __shared__ unsigned short lds_raw[];   // 2 bufs x (A 16384 + B 16384) elems
    const int tid  = threadIdx.x;
    const int lane = tid & 63;
    const int wave = tid >> 6;
    // XCD-bijective swizzle
    const int nwg = gridDim.x * gridDim.y;
    const int bid = blockIdx.y * gridDim.x + blockIdx.x;
    const int nq  = nwg >> 3;
    const int vb  = (bid & 7) * nq + (bid >> 3);
    const int bn  = (vb & (gridDim.x - 1)) * 256;
    const int bm  = (vb / gridDim.x) * 256;
    const int batch = bm >> lb;
    const int am0 = bm & ((1 << lb) - 1);
    const int Mb = 1 << lb;
    const unsigned short* Ab = A + (long)batch * sAb;
    const unsigned short* Bb = B + (long)batch * sBb;
    const long zC = (long)batch * sCb;
    const int g  = wave >> 2;            // M-group
    const int wn = (wave & 3) * 64;      // N base

    f32x4 acc[8][4];
    const f32x4 zero = {0.f, 0.f, 0.f, 0.f};
#pragma unroll
    for (int i = 0; i < 8; ++i)
#pragma unroll
        for (int j = 0; j < 4; ++j) acc[i][j] = zero;

    // stage quarter q of K-tile kt into buffer cb (2 gld_lds / thread)
    auto stageQ = [&](int kt, int cb, int q) {
        unsigned short* Lbase = lds_raw + (size_t)cb * 32768 + ((q < 2) ? 16384 : 0);
#pragma unroll
        for (int j = 0; j < 2; ++j) {
            const int c = (q & 1) * 1024 + j * 512 + tid;   // chunk in operand region
            const int row = c >> 3;
            const int klo = (c & 7) ^ (row & 7);
            if (q < 2)
                gld16(Bb + (long)(bn + row) * ldB + kt * 64 + klo * 8, Lbase + (size_t)c * 8);
            else
                gld16(Ab + (long)(am0 + row) * ldA + kt * 64 + klo * 8, Lbase + (size_t)c * 8);
        }
    };

    const int NT = K >> 6;
    // prologue: stage tile 0 fully, in steady-state FIFO order
#pragma unroll
    for (int q = 0; q < 4; ++q) stageQ(0, 0, q);

    int cur = 0;
    for (int t = 0; t < NT; ++t) {
        const int has_next = (t + 1 < NT);
        const unsigned short* LA = lds_raw + (size_t)cur * 32768;
        const unsigned short* LB = LA + 16384;
        b16x8 bfr[4][2];
#pragma unroll
        for (int p = 0; p < 4; ++p) {
            // --- vmcnt gate (counted; never 0 mid-pipeline) ---
            if (p == 0) {
                asm volatile("s_waitcnt vmcnt(2)" ::: "memory");
            } else if (p == 2) {
                if (has_next) asm volatile("s_waitcnt vmcnt(4)" ::: "memory");
                else          asm volatile("s_waitcnt vmcnt(0)" ::: "memory");
            }
            __builtin_amdgcn_sched_barrier(0);
            __builtin_amdgcn_s_barrier();
            asm volatile("" ::: "memory");
            // --- ds_read fragments ---
            if (p == 0) {
#pragma unroll
                for (int j = 0; j < 4; ++j)
#pragma unroll
                    for (int s = 0; s < 2; ++s) {
                        const int r = wn + j * 16 + (lane & 15);
                        const int kl = s * 4 + (lane >> 4);
                        bfr[j][s] = *(const b16x8*)(LB + ((size_t)r * 8 + (kl ^ (r & 7))) * 8);
                    }
            }
            b16x8 afr[2][2];
#pragma unroll
            for (int r = 0; r < 2; ++r)
#pragma unroll
                for (int s = 0; s < 2; ++s) {
                    const int row = (p >> 1) * 128 + (p & 1) * 64 + g * 32 + r * 16 + (lane & 15);
                    const int kl = s * 4 + (lane >> 4);
                    afr[r][s] = *(const b16x8*)(LA + ((size_t)row * 8 + (kl ^ (row & 7))) * 8);
                }
            // --- stage quarter p of next tile ---
            if (has_next) stageQ(t + 1, cur ^ 1, p);
            asm volatile("" ::: "memory");
            __builtin_amdgcn_s_barrier();
            __builtin_amdgcn_sched_barrier(0);
            // --- MFMA cluster ---
            __builtin_amdgcn_s_setprio(1);
#pragma unroll
            for (int r = 0; r < 2; ++r)
#pragma unroll
                for (int j = 0; j < 4; ++j)
#pragma unroll
                    for (int s = 0; s < 2; ++s)
                        acc[p * 2 + r][j] = __builtin_amdgcn_mfma_f32_16x16x32_bf16(
                            afr[r][s], bfr[j][s], acc[p * 2 + r][j], 0, 0, 0);
            __builtin_amdgcn_s_setprio(0);
        }
        cur ^= 1;
    }

    const int fl = flagp ? flagp[0] : 1;
#pragma unroll
    for (int i = 0; i < 8; ++i) {
        const int p = i >> 1, r = i & 1;
        const int rloc = am0 + (p >> 1) * 128 + (p & 1) * 64 + g * 32 + r * 16 + (lane >> 4) * 4;
#pragma unroll
        for (int j = 0; j < 4; ++j) {
            const int n = bn + wn + j * 16 + (lane & 15);
            const float bv = (MODE != 2 && bias != nullptr) ? bias[n] : 0.f;
            if (MODE == 0) {
                unsigned short* C = (unsigned short*)Cv;
#pragma unroll
                for (int rr = 0; rr < 4; ++rr)
                    C[zC + (long)(rloc + rr) * N + n] = f2bf(acc[i][j][rr] * scale + bv);
            } else if (MODE == 1) {
                unsigned short* C = (unsigned short*)Cv;
                uint32_t p0 = f2bf(acc[i][j][0] * scale + bv) |
                              ((uint32_t)f2bf(acc[i][j][1] * scale + bv) << 16);
                uint32_t p1 = f2bf(acc[i][j][2] * scale + bv) |
                              ((uint32_t)f2bf(acc[i][j][3] * scale + bv) << 16);
                uint2 val; val.x = p0; val.y = p1;
                *(uint2*)(C + zC + (long)n * Mb + rloc) = val;
            } else if (MODE == 2) {
                float* C = (float*)Cv;
#pragma unroll
                for (int rr = 0; rr < 4; ++rr)
                    C[zC + (long)(rloc + rr) * N + n] = acc[i][j][rr] * scale;
            } else {
                if (fl) {
                    float* C = (float*)Cv;
#pragma unroll
                    for (int rr = 0; rr < 4; ++rr)
                        C[zC + (long)(rloc + rr) * N + n] = acc[i][j][rr] * scale + bv;
                } else {
                    unsigned short* C = (unsigned short*)Cv;
#pragma unroll
                    for (int rr = 0; rr < 4; ++rr)
                        C[zC + (long)(rloc + rr) * N + n] = f2bf(acc[i][j][rr] * scale + bv);
                }
            }
        }
    }
}

// ---------------- row softmax over 1024 cols, IN-PLACE ----------------
__global__ __launch_bounds__(256) void k_softmax(float* __restrict__ S) {
    const long row = blockIdx.x;
    float* s = S + row * 1024;
    unsigned short* p = (unsigned short*)s;
    const int tid = threadIdx.x;
    float4 v = ((const float4*)s)[tid];
    float m = fmaxf(fmaxf(v.x, v.y), fmaxf(v.z, v.w));
#pragma unroll
    for (int o = 32; o > 0; o >>= 1) m = fmaxf(m, __shfl_xor(m, o));
    __shared__ float sm[4], ss[4];
    if ((tid & 63) == 0) sm[tid >> 6] = m;
    __syncthreads();
    m = fmaxf(fmaxf(sm[0], sm[1]), fmaxf(sm[2], sm[3]));
    float e0 = __expf(v.x - m), e1 = __expf(v.y - m);
    float e2 = __expf(v.z - m), e3 = __expf(v.w - m);
    float sum = e0 + e1 + e2 + e3;
#pragma unroll
    for (int o = 32; o > 0; o >>= 1) sum += __shfl_xor(sum, o);
    if ((tid & 63) == 0) ss[tid >> 6] = sum;
    __syncthreads();
    float inv = 1.f / (ss[0] + ss[1] + ss[2] + ss[3]);
    uint32_t w0 = f2bf(e0 * inv) | ((uint32_t)f2bf(e1 * inv) << 16);
    uint32_t w1 = f2bf(e2 * inv) | ((uint32_t)f2bf(e3 * inv) << 16);
    uint2 val; val.x = w0; val.y = w1;
    *(uint2*)(p + tid * 4) = val;
}

// ---------------- host ----------------
extern "C" void kernel_launch(void* const* d_in, const int* in_sizes, int n_in,
                              void* d_out, int out_size, void* d_ws, size_t ws_size,
                              hipStream_t stream) {
    (void)in_sizes; (void)n_in; (void)out_size; (void)ws_size;
    const void* q_in = d_in[0];   // [8,2048,512]
    const void* k_in = d_in[1];   // [8,2048,1024]
    const void* v_in = d_in[2];   // [8,2048,1024]
    const void* Wq   = d_in[3];   // [1024,512]
    const void* bq   = d_in[4];
    const void* Wk   = d_in[5];   // [1024,1024]
    const void* bk   = d_in[6];
    const void* Wv   = d_in[7];   // [1024,1024]
    const void* bv   = d_in[8];
    const void* Wo   = d_in[9];   // [1024,1024]
    const void* bo   = d_in[10];

    const size_t MB = 1u << 20;
    const size_t LDSB = 131072;   // 128 KiB dynamic LDS
    hipFuncSetAttribute((const void*)k_gemm3<0>, hipFuncAttributeMaxDynamicSharedMemorySize, (int)LDSB);
    hipFuncSetAttribute((const void*)k_gemm3<1>, hipFuncAttributeMaxDynamicSharedMemorySize, (int)LDSB);
    hipFuncSetAttribute((const void*)k_gemm3<2>, hipFuncAttributeMaxDynamicSharedMemorySize, (int)LDSB);
    hipFuncSetAttribute((const void*)k_gemm3<3>, hipFuncAttributeMaxDynamicSharedMemorySize, (int)LDSB);

    // workspace (97 MB proven): flag pad 1MB + R1(32) + R2(32) + R3(32).
    // R1: kb -> qb -> vb -> scores/P.  R2: Kt -> attn.  R3: weights bf16 + bias f32.
    // d_out: [0,32MB) Vp bf16 scratch; [32,64MB) Qt bf16 scratch; final f32 overwrites all.
    char* ws = (char*)d_ws;
    int*            flag = (int*)ws;
    unsigned short* R1   = (unsigned short*)(ws + 1 * MB);
    unsigned short* R2   = (unsigned short*)(ws + 33 * MB);
    char*           R3   = ws + 65 * MB;
    unsigned short* kb = R1, *qb = R1, *vb = R1;
    unsigned short* Kt = R2, *attn = R2;
    float*          scores = (float*)R1;
    unsigned short* P      = R1;                        // row i at i*2048 shorts
    unsigned short* wqb = (unsigned short*)R3;          // 1MB
    unsigned short* wkb = (unsigned short*)(R3 + 1 * MB);
    unsigned short* wvb = (unsigned short*)(R3 + 3 * MB);
    unsigned short* wob = (unsigned short*)(R3 + 5 * MB);
    float*          bias4 = (float*)(R3 + 7 * MB);      // bq,bk,bv,bo (f32)
    unsigned short* Vp = (unsigned short*)d_out;                     // [8,2048,1024] bf16
    unsigned short* Qt = (unsigned short*)((char*)d_out + 32 * MB);  // [8,1024,2048] bf16

    dim3 blk(256);
    k_detect<<<1, blk, 0, stream>>>((const unsigned short*)q_in, 4096, flag);
    k_cvt_bias<<<16, blk, 0, stream>>>(bq, bk, bv, bo, bias4, flag);
    k_cvt<<<256, blk, 0, stream>>>(Wq, wqb, 1024L * 512 / 8, flag);
    k_cvt<<<512, blk, 0, stream>>>(Wk, wkb, 1024L * 1024 / 8, flag);
    k_cvt<<<512, blk, 0, stream>>>(Wv, wvb, 1024L * 1024 / 8, flag);
    k_cvt<<<512, blk, 0, stream>>>(Wo, wob, 1024L * 1024 / 8, flag);

    dim3 blk5(512);
    // K path: kb -> Kt[b,j,s]
    k_cvt<<<2048, blk, 0, stream>>>(k_in, kb, 8L * 2048 * 1024 / 8, flag);
    k_gemm3<1><<<dim3(4, 64), blk5, LDSB, stream>>>(
        kb, wkb, bias4 + 1024, Kt, 1024, 1024, 1024, 1024, 11,
        2048L * 1024, 0, 1024L * 2048, 1.f, nullptr);
    // Q path: qb -> Qt[b,i,s]
    k_cvt<<<2048, blk, 0, stream>>>(q_in, qb, 8L * 2048 * 512 / 8, flag);
    k_gemm3<1><<<dim3(4, 64), blk5, LDSB, stream>>>(
        qb, wqb, bias4, Qt, 1024, 512, 512, 512, 11,
        2048L * 512, 0, 1024L * 2048, 1.f, nullptr);
    // V path: vb -> Vp[b,s,j] (M folded 16384, single batch)
    k_cvt<<<2048, blk, 0, stream>>>(v_in, vb, 8L * 2048 * 1024 / 8, flag);
    k_gemm3<0><<<dim3(4, 64), blk5, LDSB, stream>>>(
        vb, wvb, bias4 + 2 * 1024, Vp, 1024, 1024, 1024, 1024, 24,
        0, 0, 0, 1.f, nullptr);
    // scores[b,i,j] = (1/8) sum_s Qt[b,i,s]*Kt[b,j,s]  (M=8 x 1024, K=2048) -> f32
    k_gemm3<2><<<dim3(4, 32), blk5, LDSB, stream>>>(
        Qt, Kt, nullptr, scores, 1024, 2048, 2048, 2048, 10,
        1024L * 2048, 1024L * 2048, 1024L * 1024, 0.125f, nullptr);
    // softmax over j, in-place -> P (bf16, row stride 2048 shorts)
    k_softmax<<<dim3(8192), blk, 0, stream>>>(scores);
    // attn[b,s,i] = sum_j Vp[b,s,j]*P[b,i,j]  (M=8 x 2048, K=1024)
    k_gemm3<0><<<dim3(4, 64), blk5, LDSB, stream>>>(
        Vp, P, nullptr, attn, 1024, 1024, 1024, 2048, 11,
        2048L * 1024, 1024L * 2048, 2048L * 1024, 1.f, nullptr);
    // out = attn@Wo^T + bo -> d_out (f32 per flag)  (M=16384 single batch, K=1024)
    k_gemm3<3><<<dim3(4, 64), blk5, LDSB, stream>>>(
        attn, wob, bias4 + 3 * 1024, d_out, 1024, 1024, 1024, 1024, 24,
        0, 0, 0, 1.f, flag);
}